// Round 4
// baseline (262.018 us; speedup 1.0000x reference)
//
#include <hip/hip_runtime.h>

#define BATCH 4
#define N_PER 300
#define IN_DIM 256
#define KEY_DIM 32
#define FH 160
#define FW 160
#define HW (FH * FW)                 // 25600
#define NQ (BATCH * N_PER)           // 1200
#define Q_ELEMS (NQ * KEY_DIM)       // 38400 fp32 in ws: qry_feats [n][c]
#define KWT_ELEMS (IN_DIM * KEY_DIM) // 8192 fp32 in ws: key_w transposed [c][o]

#define QBLOCKS NQ                   // 1200 blocks: one per query row
#define TBLOCKS (KWT_ELEMS / 256)    // 32 transpose blocks
#define PXB 64                       // pixels per block (one per lane)
#define NQUAR (N_PER / 4)            // 75 queries per wave
#define CQUAR (IN_DIM / 4)           // 64 channels per wave

// ---------------------------------------------------------------------------
// Prep (unchanged — fast since round 1):
// Blocks [0,1200): block n computes qry_feats[n][0..32) via float4 dot +
// 3x shfl_xor k-reduce.  Blocks [1200,1232): transpose key_w -> kwT[c][o].
// ---------------------------------------------------------------------------
__global__ __launch_bounds__(256) void prep_kernel(
        const float* __restrict__ in_feats,
        const float* __restrict__ qry_w,
        const float* __restrict__ qry_b,
        const float* __restrict__ key_w,
        float* __restrict__ ws) {
    const int bid = blockIdx.x;
    const int t = threadIdx.x;
    if (bid < QBLOCKS) {
        const int n   = bid;
        const int c   = t >> 3;      // 0..31
        const int sub = t & 7;       // 0..7  (k-chunk)
        const float4* __restrict__ f4 =
            (const float4*)(in_feats + n * IN_DIM + sub * 32);
        const float4* __restrict__ w4 =
            (const float4*)(qry_w + c * IN_DIM + sub * 32);
        float a0 = 0.f, a1 = 0.f, a2 = 0.f, a3 = 0.f;
        #pragma unroll
        for (int j = 0; j < 8; ++j) {
            float4 fv = f4[j];
            float4 wv = w4[j];
            a0 += fv.x * wv.x;
            a1 += fv.y * wv.y;
            a2 += fv.z * wv.z;
            a3 += fv.w * wv.w;
        }
        float s = (a0 + a1) + (a2 + a3);
        s += __shfl_xor(s, 1);
        s += __shfl_xor(s, 2);
        s += __shfl_xor(s, 4);
        if (sub == 0) ws[n * KEY_DIM + c] = s + qry_b[c];
    } else {
        const int i = (bid - QBLOCKS) * 256 + t;   // 0..8191
        const int c = i >> 5;                      // 0..255
        const int o = i & 31;                      // 0..31
        ws[Q_ELEMS + i] = key_w[o * IN_DIM + c];   // kwT[c*32 + o]
    }
}

// ---------------------------------------------------------------------------
// Fused main v5: 64-pixel blocks, 4 waves = 4 channel-groups -> 1600 blocks
// x 4 waves = 6400 waves (2x v4's 3200; v4 was wave-count starved at 31%
// occupancy with per-wave VALU duty already ~80%).
//
//   lane l = pixel within tile (feat loads / out stores: 64x4B = 256 B
//   contiguous per wave-inst, coalesced).  wave w (SGPR via readfirstlane,
//   preserving v4's scalarization of all weight/query loads):
//     phase 1: accumulate key over channels [w*64, w*64+64).
//     reduce:  all waves write part[w][o][l] (lane-indexed last -> 2 lanes/
//              bank, conflict-free); wave w sums its 8-channel o-slice
//              (+key_b) back into part[0]; barrier; all read final key.
//     phase 2: wave w handles 75 queries (n = w*75+j wave-uniform -> q rows
//              stay s_loads; unroll 2 pipelines next row's s_load under FMAs).
// LDS 32 KB -> 5 blocks/CU -> 20 waves/CU cap (62.5%).
// ---------------------------------------------------------------------------
__global__ __launch_bounds__(256) void main_kernel(
        const float* __restrict__ feat_map,
        const float* __restrict__ key_b,
        const float* __restrict__ ws,
        float* __restrict__ out) {
    __shared__ float part[4][KEY_DIM][PXB];        // 32 KB

    const int t   = threadIdx.x;
    const int l   = t & 63;                                   // pixel lane
    const int w   = __builtin_amdgcn_readfirstlane(t >> 6);   // wave 0..3, SGPR
    const int b   = blockIdx.y;
    const int pix = blockIdx.x * PXB + l;

    const float* __restrict__ fb  =
        feat_map + ((size_t)b * IN_DIM + w * CQUAR) * HW + pix;
    const float* __restrict__ kwT = ws + Q_ELEMS + (w * CQUAR) * KEY_DIM;

    float acc[KEY_DIM];
    #pragma unroll
    for (int o = 0; o < KEY_DIM; ++o) acc[o] = 0.f;

    // Phase 1: 64 coalesced feat loads, 64x32 FMA; kwT rows are s_loads.
    #pragma unroll 8
    for (int c = 0; c < CQUAR; ++c) {
        float f = fb[(size_t)c * HW];
        const float* __restrict__ kr = kwT + c * KEY_DIM;
        #pragma unroll
        for (int o = 0; o < KEY_DIM; ++o) acc[o] += kr[o] * f;
    }

    // Cross-wave reduction (balanced): every wave writes its 32 partials,
    // wave w reduces output channels [w*8, w*8+8) into part[0].
    #pragma unroll
    for (int o = 0; o < KEY_DIM; ++o) part[w][o][l] = acc[o];
    __syncthreads();
    #pragma unroll
    for (int i = 0; i < 8; ++i) {
        const int o = w * 8 + i;                   // wave-uniform
        float s = part[0][o][l] + part[1][o][l]
                + part[2][o][l] + part[3][o][l] + key_b[o];
        part[0][o][l] = s;                         // disjoint o-slices: no race
    }
    __syncthreads();

    float key[KEY_DIM];
    #pragma unroll
    for (int o = 0; o < KEY_DIM; ++o) key[o] = part[0][o][l];

    // Phase 2: 75 dot-32s per lane against wave-uniform (s_load) q rows.
    const float* __restrict__ qb =
        ws + ((size_t)b * N_PER + w * NQUAR) * KEY_DIM;
    float* __restrict__ ob =
        out + ((size_t)b * N_PER + (size_t)w * NQUAR) * HW + pix;

    #pragma unroll 2
    for (int n = 0; n < NQUAR; ++n) {
        const float* __restrict__ qn = qb + n * KEY_DIM;
        float a0 = 0.f, a1 = 0.f, a2 = 0.f, a3 = 0.f;
        #pragma unroll
        for (int c2 = 0; c2 < KEY_DIM; c2 += 4) {
            a0 += qn[c2 + 0] * key[c2 + 0];
            a1 += qn[c2 + 1] * key[c2 + 1];
            a2 += qn[c2 + 2] * key[c2 + 2];
            a3 += qn[c2 + 3] * key[c2 + 3];
        }
        ob[(size_t)n * HW] = (a0 + a1) + (a2 + a3);
    }
}

extern "C" void kernel_launch(void* const* d_in, const int* in_sizes, int n_in,
                              void* d_out, int out_size, void* d_ws, size_t ws_size,
                              hipStream_t stream) {
    const float* in_feats = (const float*)d_in[0];  // [1200, 256]
    const float* feat_map = (const float*)d_in[1];  // [4, 256, 160, 160]
    const float* qry_w    = (const float*)d_in[2];  // [32, 256]
    const float* qry_b    = (const float*)d_in[3];  // [32]
    const float* key_w    = (const float*)d_in[4];  // [32, 256]
    const float* key_b    = (const float*)d_in[5];  // [32]
    float* ws  = (float*)d_ws;                      // needs 46592*4 B
    float* out = (float*)d_out;                     // [1200, 160, 160] fp32

    // Prep: 1200 q-blocks + 32 transpose blocks.
    prep_kernel<<<dim3(QBLOCKS + TBLOCKS), dim3(256), 0, stream>>>(
        in_feats, qry_w, qry_b, key_w, ws);

    // Main: 400 pixel-tiles (64 px) x 4 batches = 1600 blocks, 6400 waves.
    main_kernel<<<dim3(HW / PXB, BATCH), dim3(256), 0, stream>>>(
        feat_map, key_b, ws, out);
}